// Round 6
// baseline (528.046 us; speedup 1.0000x reference)
//
#include <hip/hip_runtime.h>
#include <cstdint>
#include <cstddef>

typedef short v8s __attribute__((ext_vector_type(8)));
typedef float v4f __attribute__((ext_vector_type(4)));

__device__ inline float bs2f(short s) {
    return __uint_as_float(((unsigned int)(unsigned short)s) << 16);
}
__device__ inline short f2bs(float f) {
    unsigned int u = __float_as_uint(f);
    unsigned int r = (u + 0x7fffu + ((u >> 16) & 1u)) >> 16;  // RNE
    return (short)r;
}

#define MFMA(a, b, c) __builtin_amdgcn_mfma_f32_16x16x32_bf16((a), (b), (c), 0, 0, 0)

// async global->LDS, 16B per lane, LDS dest = wave-uniform base + lane*16
#define GLOAD_LDS16(g, l)                                                  \
    __builtin_amdgcn_global_load_lds(                                      \
        (const __attribute__((address_space(1))) void*)(g),                \
        (__attribute__((address_space(3))) void*)(l), 16, 0, 0)

// ---------------------------------------------------- fused preprocessing
// blk [0,8192):        x fp32 -> xb bf16 (4 elems/thread)
// blk [8192,19456):    W transposes fp32[K,N] -> bf16[N,K]
__global__ __launch_bounds__(256) void prep(const float* __restrict__ x,
                                            short* __restrict__ xb,
                                            const float* __restrict__ Wq,
                                            const float* __restrict__ Wkv,
                                            const float* __restrict__ Wkr,
                                            const float* __restrict__ Wkn,
                                            const float* __restrict__ Wv,
                                            const float* __restrict__ Wo,
                                            short* __restrict__ WtA,
                                            short* __restrict__ WtB,
                                            short* __restrict__ Wot) {
    int blk = blockIdx.x;
    if (blk < 8192) {
        int i = (blk * 256 + threadIdx.x) * 4;
        float4 v = *(const float4*)(x + i);
        short r[4] = {f2bs(v.x), f2bs(v.y), f2bs(v.z), f2bs(v.w)};
        *(uint2*)(xb + i) = *(const uint2*)r;
        return;
    }
    blk -= 8192;
    const float* W;
    short* Wt;
    int K, N, bx, by;
    if (blk < 4096)      { W = Wq;  Wt = WtA;                      K = 2048; N = 2048; bx = blk & 63; by = blk >> 6; }
    else if (blk < 5120) { blk -= 4096; W = Wkv; Wt = WtA + (size_t)2048 * 2048; K = 2048; N = 512;  bx = blk & 15; by = blk >> 4; }
    else if (blk < 5632) { blk -= 5120; W = Wkr; Wt = WtB;                       K = 512;  N = 1024; bx = blk & 31; by = blk >> 5; }
    else if (blk < 6144) { blk -= 5632; W = Wkn; Wt = WtB + (size_t)1024 * 512;  K = 512;  N = 1024; bx = blk & 31; by = blk >> 5; }
    else if (blk < 7168) { blk -= 6144; W = Wv;  Wt = WtB + (size_t)2048 * 512;  K = 512;  N = 2048; bx = blk & 63; by = blk >> 6; }
    else                 { blk -= 7168; W = Wo;  Wt = Wot;                       K = 2048; N = 2048; bx = blk & 63; by = blk >> 6; }

    __shared__ float tile[32][33];
    const int tx = threadIdx.x & 31, ty = threadIdx.x >> 5;  // ty 0..7
    const int n0 = bx * 32, k0 = by * 32;
#pragma unroll
    for (int i = 0; i < 32; i += 8) tile[ty + i][tx] = W[(size_t)(k0 + ty + i) * N + n0 + tx];
    __syncthreads();
#pragma unroll
    for (int i = 0; i < 32; i += 8)
        Wt[(size_t)(n0 + ty + i) * K + k0 + tx] = f2bs(tile[tx][ty + i]);
}

// ----------------------------------------------------------------- GEMM B^T
// C = A[M,K] @ B[K,N], Bt = B^T [N,K] bf16. 128x128 tile, 4 waves, 4x4 MFMA
// 16x16x32 per wave. Staging via global_load_lds (16B), packed LDS 128x32
// shorts per tile, XOR swizzle: chunk c of row r stored at slot c^((r>>1)&3).
// mode 1: f32  C0[M,N]
// mode 2: col<2048 -> fused per-head RMSNorm (g,scale) -> C0 bf16 ld 2048
//         else -> C1 bf16 ld 512 (col-2048)
// mode 3: col<1024 -> C0 ld 1024 ; col<2048 -> C1 ld 1024 ; else transposed V
//         write to C2: C2[((row>>11)*16 + (c>>7))*128 + (c&127)][row&2047], c=col-2048
__global__ __launch_bounds__(256) void gemm_bt(const short* __restrict__ A,
                                               const short* __restrict__ Bt,
                                               void* __restrict__ C0,
                                               void* __restrict__ C1,
                                               void* __restrict__ C2,
                                               int M, int N, int K, int mode,
                                               const float* __restrict__ g,
                                               float scale) {
    __shared__ short As[128 * 32];
    __shared__ short Bs[128 * 32];
    const int tid = threadIdx.x;
    const int lane = tid & 63, wave = tid >> 6;
    const int l16 = lane & 15, quad = lane >> 4;
    const int wm = (wave >> 1) * 64, wn = (wave & 1) * 64;
    const int m0 = blockIdx.y * 128, n0 = blockIdx.x * 128;

    const v4f VZ = {0.f, 0.f, 0.f, 0.f};
    v4f acc[4][4];
#pragma unroll
    for (int i = 0; i < 4; i++)
#pragma unroll
        for (int j = 0; j < 4; j++) acc[i][j] = VZ;

    // staging: wave covers rows [wave*32, wave*32+32), two 16-row calls each
    const int r0 = wave * 32 + (lane >> 2);
    const int r1 = r0 + 16;
    const int c0 = ((lane & 3) ^ ((r0 >> 1) & 3)) * 8;
    const int c1 = ((lane & 3) ^ ((r1 >> 1) & 3)) * 8;
    const short* aSrc0 = A + (size_t)(m0 + r0) * K + c0;
    const short* aSrc1 = A + (size_t)(m0 + r1) * K + c1;
    const short* bSrc0 = Bt + (size_t)(n0 + r0) * K + c0;
    const short* bSrc1 = Bt + (size_t)(n0 + r1) * K + c1;
    short* const ldsA0 = &As[(wave * 32) * 32];
    short* const ldsA1 = &As[(wave * 32 + 16) * 32];
    short* const ldsB0 = &Bs[(wave * 32) * 32];
    short* const ldsB1 = &Bs[(wave * 32 + 16) * 32];

    for (int kk = 0; kk < K; kk += 32) {
        __syncthreads();  // previous iteration's fragment reads complete
        GLOAD_LDS16(aSrc0 + kk, ldsA0);
        GLOAD_LDS16(aSrc1 + kk, ldsA1);
        GLOAD_LDS16(bSrc0 + kk, ldsB0);
        GLOAD_LDS16(bSrc1 + kk, ldsB1);
        __syncthreads();  // drain global_load_lds

        v8s af[4], bfr[4];
#pragma unroll
        for (int t = 0; t < 4; t++) {
            const int ra = wm + t * 16 + l16;
            af[t] = *(const v8s*)(&As[ra * 32 + ((quad ^ ((ra >> 1) & 3)) * 8)]);
        }
#pragma unroll
        for (int t = 0; t < 4; t++) {
            const int rb = wn + t * 16 + l16;
            bfr[t] = *(const v8s*)(&Bs[rb * 32 + ((quad ^ ((rb >> 1) & 3)) * 8)]);
        }
#pragma unroll
        for (int i = 0; i < 4; i++)
#pragma unroll
            for (int j = 0; j < 4; j++) acc[i][j] = MFMA(af[i], bfr[j], acc[i][j]);
    }

    if (mode == 2) {
        if (n0 < 2048) {
            // fused per-head RMSNorm: this tile's 128 cols = exactly head n0>>7
            __syncthreads();  // all waves done with As fragment reads
            float* red = (float*)As;  // [128 rows][2 wn-halves]
#pragma unroll
            for (int i = 0; i < 4; i++) {
#pragma unroll
                for (int r = 0; r < 4; r++) {
                    float ss2 = 0.f;
#pragma unroll
                    for (int j = 0; j < 4; j++) { float v = acc[i][j][r]; ss2 += v * v; }
#pragma unroll
                    for (int off2 = 1; off2 < 16; off2 <<= 1) ss2 += __shfl_xor(ss2, off2);
                    if (l16 == 0) red[(wm + i * 16 + quad * 4 + r) * 2 + (wn >> 6)] = ss2;
                }
            }
            __syncthreads();
            float gv[4];
#pragma unroll
            for (int j = 0; j < 4; j++) gv[j] = g[wn + j * 16 + l16];
#pragma unroll
            for (int i = 0; i < 4; i++) {
#pragma unroll
                for (int r = 0; r < 4; r++) {
                    const int rl = wm + i * 16 + quad * 4 + r;
                    const float rs =
                        rsqrtf((red[rl * 2] + red[rl * 2 + 1]) * (1.f / 128.f) + 1e-6f) * scale;
#pragma unroll
                    for (int j = 0; j < 4; j++)
                        ((short*)C0)[(size_t)(m0 + rl) * 2048 + n0 + wn + j * 16 + l16] =
                            f2bs(acc[i][j][r] * rs * gv[j]);
                }
            }
        } else {
#pragma unroll
            for (int i = 0; i < 4; i++)
#pragma unroll
                for (int r = 0; r < 4; r++) {
                    const int row = m0 + wm + i * 16 + quad * 4 + r;
#pragma unroll
                    for (int j = 0; j < 4; j++)
                        ((short*)C1)[(size_t)row * 512 + n0 - 2048 + wn + j * 16 + l16] =
                            f2bs(acc[i][j][r]);
                }
        }
        return;
    }

    if (mode == 3 && n0 >= 2048) {
        // transposed bf16 V epilogue; pack 4 consecutive tokens per 8B store
        short* C = (short*)C2;
#pragma unroll
        for (int i = 0; i < 4; i++) {
            const int row = m0 + wm + i * 16 + quad * 4;  // token (r=0 base)
#pragma unroll
            for (int j = 0; j < 4; j++) {
                const int col = n0 - 2048 + wn + j * 16 + l16;  // h*128+d
                size_t base = ((size_t)((row >> 11) * 16 + (col >> 7)) * 128 + (col & 127)) * 2048
                              + (row & 2047);
                short pk[4];
#pragma unroll
                for (int r = 0; r < 4; r++) pk[r] = f2bs(acc[i][j][r]);
                *(uint2*)(C + base) = *(const uint2*)pk;
            }
        }
        return;
    }

    // mode 1 (f32 flat) and mode 3 flat parts
    void* Cb = C0;
    int ld = N, coff = 0;
    if (mode == 3) {
        if (n0 < 1024) { Cb = C0; ld = 1024; coff = 0; }
        else           { Cb = C1; ld = 1024; coff = 1024; }
    }
#pragma unroll
    for (int i = 0; i < 4; i++) {
#pragma unroll
        for (int r = 0; r < 4; r++) {
            const int row = m0 + wm + i * 16 + quad * 4 + r;
#pragma unroll
            for (int j = 0; j < 4; j++) {
                const int col = n0 - coff + wn + j * 16 + l16;
                float v = acc[i][j][r];
                if (mode == 1) ((float*)Cb)[(size_t)row * ld + col] = v;
                else ((short*)Cb)[(size_t)row * ld + col] = f2bs(v);
            }
        }
    }
}

// ------------------------------------------------------------- RMSNorm (k)
__global__ __launch_bounds__(256) void rmsnorm_k(const short* __restrict__ KR,
                                                 const short* __restrict__ KN,
                                                 const float* __restrict__ g,
                                                 short* __restrict__ Y) {
    const int rh = blockIdx.x * 4 + (threadIdx.x >> 6);  // m*16+h
    const int m = rh >> 4, h = rh & 15;
    const int lane = threadIdx.x & 63;
    float a = bs2f(KR[(size_t)m * 1024 + h * 64 + lane]);
    float c = bs2f(KN[(size_t)m * 1024 + h * 64 + lane]);
    float ss = a * a + c * c;
#pragma unroll
    for (int off = 1; off < 64; off <<= 1) ss += __shfl_xor(ss, off);
    float rs = rsqrtf(ss * (1.f / 128.f) + 1e-6f);
    Y[(size_t)rh * 128 + lane] = f2bs(a * rs * g[lane]);
    Y[(size_t)rh * 128 + 64 + lane] = f2bs(c * rs * g[lane + 64]);
}

// ------------------------------------------------------ flash attention (causal)
// Q,K,O: bf16 [B,S,H,D]; V pre-transposed: vT[((b*16+h)*128+d)*S + s].
// 1024 blocks x 2 waves; wave0 -> q-wave p, wave1 -> q-wave 63-p  =>
// every block = exactly 33 k-tiles (perfect CU balance). 32 q-rows/wave,
// 64-key tiles, S^T = K Q^T, direct-from-global K/V fragments (L1/L2 reuse),
// wave-private LDS for the P layout round-trip, no __syncthreads anywhere.
// log2(e) folded into q scale -> exp2f. Wave-uniform skip of the rescale
// path when no lane sees a new max.
#define PSTR 72   // Ps [qrow][key] row stride in shorts

__global__ __launch_bounds__(128) void flash_attn(const short* __restrict__ Q,
                                                  const short* __restrict__ Kb,
                                                  const short* __restrict__ vT,
                                                  short* __restrict__ O, int S) {
    __shared__ short Ps[2][32 * PSTR];

    const int lane = threadIdx.x & 63, w = threadIdx.x >> 6;
    const int l16 = lane & 15, quad = lane >> 4;
    const int blk = blockIdx.x;            // 1024
    const int g = blk >> 3;
    const int bh = ((g & 3) << 3) | (blk & 7);  // low 3 bits -> XCD locality
    const int b = bh >> 4, h = bh & 15;
    const int pair = g >> 2;               // 0..31
    const int qw = w == 0 ? pair : 63 - pair;
    const int wq0 = qw * 32;               // this wave's first q-row

    // Q fragments (B-operand): lane l16 = q-col, quad*8+j = d
    v8s bq[2][4];
#pragma unroll
    for (int qs = 0; qs < 2; qs++) {
        const size_t qbase = ((size_t)(b * S + wq0 + qs * 16 + l16) * 16 + h) * 128;
#pragma unroll
        for (int kc = 0; kc < 4; kc++)
            bq[qs][kc] = *(const v8s*)(Q + qbase + kc * 32 + quad * 8);
    }

    const v4f VZ = {0.f, 0.f, 0.f, 0.f};
    v4f accO[2][8];
#pragma unroll
    for (int qs = 0; qs < 2; qs++)
#pragma unroll
        for (int d = 0; d < 8; d++) accO[qs][d] = VZ;
    float m_i[2] = {-1e30f, -1e30f}, l_i[2] = {0.f, 0.f};

    const short* const kbh = Kb + ((size_t)b * S * 16 + h) * 128;  // + key*2048 + d
    const short* const vbh = vT + (size_t)bh * 128 * S;            // + d*S + key

    const int nkt = ((wq0 + 31) >> 6) + 1;
    for (int kt = 0; kt < nkt; ++kt) {
        const int k0 = kt * 64;

        // S^T tile = K Q^T: rows = keys (quad*4+r), cols = q (l16)
        v4f sc[2][4];
#pragma unroll
        for (int nt = 0; nt < 4; nt++) {
            v8s ak[4];
            const short* krow = kbh + (size_t)(k0 + nt * 16 + l16) * 2048 + quad * 8;
#pragma unroll
            for (int kc = 0; kc < 4; kc++) ak[kc] = *(const v8s*)(krow + kc * 32);
#pragma unroll
            for (int qs = 0; qs < 2; qs++) {
                v4f s = VZ;
#pragma unroll
                for (int kc = 0; kc < 4; kc++) s = MFMA(ak[kc], bq[qs][kc], s);
                sc[qs][nt] = s;
            }
        }

        // causal mask: only the final (diagonal) tile
        if (kt == nkt - 1) {
#pragma unroll
            for (int qs = 0; qs < 2; qs++) {
                const int qrow = wq0 + qs * 16 + l16;
#pragma unroll
                for (int nt = 0; nt < 4; nt++)
#pragma unroll
                    for (int r = 0; r < 4; r++)
                        if (k0 + nt * 16 + quad * 4 + r > qrow) sc[qs][nt][r] = -1e30f;
            }
        }

        // online softmax per q-subtile (lane owns q-col l16)
#pragma unroll
        for (int qs = 0; qs < 2; qs++) {
            float tmax = -1e30f;
#pragma unroll
            for (int nt = 0; nt < 4; nt++)
#pragma unroll
                for (int r = 0; r < 4; r++) tmax = fmaxf(tmax, sc[qs][nt][r]);
            tmax = fmaxf(tmax, __shfl_xor(tmax, 16));
            tmax = fmaxf(tmax, __shfl_xor(tmax, 32));
            const bool upd = __any(tmax > m_i[qs]);  // wave-uniform
            float alpha = 1.f;
            if (upd) {
                const float mnew = fmaxf(m_i[qs], tmax);
                alpha = exp2f(m_i[qs] - mnew);
                m_i[qs] = mnew;
            }
            const float mcur = m_i[qs];
            float rsum = 0.f;
#pragma unroll
            for (int nt = 0; nt < 4; nt++) {
                short pk[4];
#pragma unroll
                for (int r = 0; r < 4; r++) {
                    float p = exp2f(sc[qs][nt][r] - mcur);
                    rsum += p;
                    pk[r] = (short)(__float_as_uint(p) >> 16);  // truncating bf16
                }
                *(uint2*)(&Ps[w][(qs * 16 + l16) * PSTR + nt * 16 + quad * 4]) =
                    *(const uint2*)pk;
            }
            rsum += __shfl_xor(rsum, 16);
            rsum += __shfl_xor(rsum, 32);
            if (upd) {
                l_i[qs] = l_i[qs] * alpha + rsum;
                float ar[4];
#pragma unroll
                for (int r = 0; r < 4; r++) ar[r] = __shfl(alpha, quad * 4 + r);
#pragma unroll
                for (int dt = 0; dt < 8; dt++)
#pragma unroll
                    for (int r = 0; r < 4; r++) accO[qs][dt][r] *= ar[r];
            } else {
                l_i[qs] += rsum;
            }
        }

        // O += P V  (P: A-layout from wave-private LDS; V: direct from global)
        v8s ap[2][2];
#pragma unroll
        for (int qs = 0; qs < 2; qs++)
#pragma unroll
            for (int kc2 = 0; kc2 < 2; kc2++)
                ap[qs][kc2] =
                    *(const v8s*)(&Ps[w][(qs * 16 + l16) * PSTR + kc2 * 32 + quad * 8]);
#pragma unroll
        for (int dt = 0; dt < 8; dt++) {
            const short* vrow = vbh + (size_t)(dt * 16 + l16) * S + k0 + quad * 8;
#pragma unroll
            for (int kc2 = 0; kc2 < 2; kc2++) {
                v8s bv = *(const v8s*)(vrow + kc2 * 32);
#pragma unroll
                for (int qs = 0; qs < 2; qs++)
                    accO[qs][dt] = MFMA(ap[qs][kc2], bv, accO[qs][dt]);
            }
        }
    }

#pragma unroll
    for (int qs = 0; qs < 2; qs++) {
#pragma unroll
        for (int r = 0; r < 4; r++) {
            const int qg = wq0 + qs * 16 + quad * 4 + r;
            const float inv = 1.f / __shfl(l_i[qs], quad * 4 + r);
            const size_t obase = ((size_t)(b * S + qg) * 16 + h) * 128;
#pragma unroll
            for (int dt = 0; dt < 8; dt++)
                O[obase + dt * 16 + l16] = f2bs(accO[qs][dt][r] * inv);
        }
    }
}

// ---------------------------------------------------------------------------
extern "C" void kernel_launch(void* const* d_in, const int* in_sizes, int n_in,
                              void* d_out, int out_size, void* d_ws, size_t ws_size,
                              hipStream_t stream) {
    (void)in_sizes; (void)n_in; (void)out_size; (void)ws_size;
    const float* x   = (const float*)d_in[0];
    const float* Wq  = (const float*)d_in[1];
    const float* Wkv = (const float*)d_in[2];
    const float* Wkr = (const float*)d_in[3];
    const float* Wkn = (const float*)d_in[4];
    const float* Wv  = (const float*)d_in[5];
    const float* Wo  = (const float*)d_in[6];
    const float* gq  = (const float*)d_in[7];
    const float* gk  = (const float*)d_in[8];

    const int B = 2, S = 2048, HID = 2048;
    const int M = B * S;  // 4096

    char* ws = (char*)d_ws;
    size_t off = 0;
    auto alloc = [&](size_t bytes) {
        char* p = ws + off;
        off += (bytes + 255) & ~(size_t)255;
        return p;
    };
    short* xb   = (short*)alloc((size_t)M * HID * 2);
    short* WtA  = (short*)alloc((size_t)2560 * 2048 * 2);  // [Wq^T | Wkv^T]
    short* WtB  = (short*)alloc((size_t)4096 * 512 * 2);   // [Wkr^T | Wkn^T | Wv^T]
    short* Wot  = (short*)alloc((size_t)2048 * 2048 * 2);
    short* qb   = (short*)alloc((size_t)M * 2048 * 2);
    short* lat  = (short*)alloc((size_t)M * 512 * 2);
    short* krr  = (short*)alloc((size_t)M * 1024 * 2);
    short* knr  = (short*)alloc((size_t)M * 1024 * 2);
    short* kb   = (short*)alloc((size_t)M * 2048 * 2);
    short* vT   = (short*)alloc((size_t)M * 2048 * 2);  // [B*H][128][S]
    short* ob   = (short*)alloc((size_t)M * 2048 * 2);

    // fused conversion + transposes (single launch)
    prep<<<19456, 256, 0, stream>>>(x, xb, Wq, Wkv, Wkr, Wkn, Wv, Wo, WtA, WtB, Wot);

    // GEMM-A: x @ [Wq | Wkv] -> qb (fused per-head RMSNorm, scale incl log2e) + lat
    gemm_bt<<<dim3(2560 / 128, M / 128), 256, 0, stream>>>(
        xb, WtA, qb, lat, nullptr, M, 2560, 2048, 2, gq,
        0.08838834764831845f * 1.4426950408889634f);

    // GEMM-B: lat @ [Wkr | Wkn | Wv] -> krr, knr, vT(transposed)
    gemm_bt<<<dim3(4096 / 128, M / 128), 256, 0, stream>>>(
        lat, WtB, krr, knr, vT, M, 4096, 512, 3, nullptr, 0.f);
    rmsnorm_k<<<(M * 16) / 4, 256, 0, stream>>>(krr, knr, gk, kb);

    // causal SDPA: 1024 equal-work blocks x 2 waves
    flash_attn<<<dim3(1024), 128, 0, stream>>>(qb, kb, vT, ob, S);

    // GEMM-C: out = o @ Wo (fp32)
    gemm_bt<<<dim3(2048 / 128, M / 128), 256, 0, stream>>>(
        ob, Wot, d_out, nullptr, nullptr, M, 2048, 2048, 1, nullptr, 0.f);
}

// Round 7
// 477.799 us; speedup vs baseline: 1.1052x; 1.1052x over previous
//
#include <hip/hip_runtime.h>
#include <cstdint>
#include <cstddef>

typedef short v8s __attribute__((ext_vector_type(8)));
typedef float v4f __attribute__((ext_vector_type(4)));

__device__ inline float bs2f(short s) {
    return __uint_as_float(((unsigned int)(unsigned short)s) << 16);
}
__device__ inline short f2bs(float f) {
    unsigned int u = __float_as_uint(f);
    unsigned int r = (u + 0x7fffu + ((u >> 16) & 1u)) >> 16;  // RNE
    return (short)r;
}

#define MFMA(a, b, c) __builtin_amdgcn_mfma_f32_16x16x32_bf16((a), (b), (c), 0, 0, 0)

// async global->LDS, 16B per lane, LDS dest = wave-uniform base + lane*16
#define GLOAD_LDS16(g, l)                                                  \
    __builtin_amdgcn_global_load_lds(                                      \
        (const __attribute__((address_space(1))) void*)(g),                \
        (__attribute__((address_space(3))) void*)(l), 16, 0, 0)

// ---------------------------------------------------- fused preprocessing
__global__ __launch_bounds__(256) void prep(const float* __restrict__ x,
                                            short* __restrict__ xb,
                                            const float* __restrict__ Wq,
                                            const float* __restrict__ Wkv,
                                            const float* __restrict__ Wkr,
                                            const float* __restrict__ Wkn,
                                            const float* __restrict__ Wv,
                                            const float* __restrict__ Wo,
                                            short* __restrict__ WtA,
                                            short* __restrict__ WtB,
                                            short* __restrict__ Wot) {
    int blk = blockIdx.x;
    if (blk < 8192) {
        int i = (blk * 256 + threadIdx.x) * 4;
        float4 v = *(const float4*)(x + i);
        short r[4] = {f2bs(v.x), f2bs(v.y), f2bs(v.z), f2bs(v.w)};
        *(uint2*)(xb + i) = *(const uint2*)r;
        return;
    }
    blk -= 8192;
    const float* W;
    short* Wt;
    int K, N, bx, by;
    if (blk < 4096)      { W = Wq;  Wt = WtA;                      K = 2048; N = 2048; bx = blk & 63; by = blk >> 6; }
    else if (blk < 5120) { blk -= 4096; W = Wkv; Wt = WtA + (size_t)2048 * 2048; K = 2048; N = 512;  bx = blk & 15; by = blk >> 4; }
    else if (blk < 5632) { blk -= 5120; W = Wkr; Wt = WtB;                       K = 512;  N = 1024; bx = blk & 31; by = blk >> 5; }
    else if (blk < 6144) { blk -= 5632; W = Wkn; Wt = WtB + (size_t)1024 * 512;  K = 512;  N = 1024; bx = blk & 31; by = blk >> 5; }
    else if (blk < 7168) { blk -= 6144; W = Wv;  Wt = WtB + (size_t)2048 * 512;  K = 512;  N = 2048; bx = blk & 63; by = blk >> 6; }
    else                 { blk -= 7168; W = Wo;  Wt = Wot;                       K = 2048; N = 2048; bx = blk & 63; by = blk >> 6; }

    __shared__ float tile[32][33];
    const int tx = threadIdx.x & 31, ty = threadIdx.x >> 5;  // ty 0..7
    const int n0 = bx * 32, k0 = by * 32;
#pragma unroll
    for (int i = 0; i < 32; i += 8) tile[ty + i][tx] = W[(size_t)(k0 + ty + i) * N + n0 + tx];
    __syncthreads();
#pragma unroll
    for (int i = 0; i < 32; i += 8)
        Wt[(size_t)(n0 + ty + i) * K + k0 + tx] = f2bs(tile[tx][ty + i]);
}

// ----------------------------------------------------------------- GEMM B^T
// C = A[M,K] @ B[K,N], Bt = B^T [N,K] bf16. 128x128 tile, 4 waves, 4x4 MFMA
// 16x16x32 per wave. global_load_lds staging, packed LDS 128x32, XOR swizzle.
// mode 1: f32  C0[M,N]
// mode 2: col<2048 -> fused per-head RMSNorm (g,scale) -> C0 bf16 ld 2048
//         else -> C1 bf16 ld 512 (col-2048)
// mode 3: col<1024 -> C0 ld 1024 ; col<2048 -> C1 ld 1024 ; else transposed V
__global__ __launch_bounds__(256) void gemm_bt(const short* __restrict__ A,
                                               const short* __restrict__ Bt,
                                               void* __restrict__ C0,
                                               void* __restrict__ C1,
                                               void* __restrict__ C2,
                                               int M, int N, int K, int mode,
                                               const float* __restrict__ g,
                                               float scale) {
    __shared__ short As[128 * 32];
    __shared__ short Bs[128 * 32];
    const int tid = threadIdx.x;
    const int lane = tid & 63, wave = tid >> 6;
    const int l16 = lane & 15, quad = lane >> 4;
    const int wm = (wave >> 1) * 64, wn = (wave & 1) * 64;
    const int m0 = blockIdx.y * 128, n0 = blockIdx.x * 128;

    const v4f VZ = {0.f, 0.f, 0.f, 0.f};
    v4f acc[4][4];
#pragma unroll
    for (int i = 0; i < 4; i++)
#pragma unroll
        for (int j = 0; j < 4; j++) acc[i][j] = VZ;

    const int r0 = wave * 32 + (lane >> 2);
    const int r1 = r0 + 16;
    const int c0 = ((lane & 3) ^ ((r0 >> 1) & 3)) * 8;
    const int c1 = ((lane & 3) ^ ((r1 >> 1) & 3)) * 8;
    const short* aSrc0 = A + (size_t)(m0 + r0) * K + c0;
    const short* aSrc1 = A + (size_t)(m0 + r1) * K + c1;
    const short* bSrc0 = Bt + (size_t)(n0 + r0) * K + c0;
    const short* bSrc1 = Bt + (size_t)(n0 + r1) * K + c1;
    short* const ldsA0 = &As[(wave * 32) * 32];
    short* const ldsA1 = &As[(wave * 32 + 16) * 32];
    short* const ldsB0 = &Bs[(wave * 32) * 32];
    short* const ldsB1 = &Bs[(wave * 32 + 16) * 32];

    for (int kk = 0; kk < K; kk += 32) {
        __syncthreads();
        GLOAD_LDS16(aSrc0 + kk, ldsA0);
        GLOAD_LDS16(aSrc1 + kk, ldsA1);
        GLOAD_LDS16(bSrc0 + kk, ldsB0);
        GLOAD_LDS16(bSrc1 + kk, ldsB1);
        __syncthreads();

        v8s af[4], bfr[4];
#pragma unroll
        for (int t = 0; t < 4; t++) {
            const int ra = wm + t * 16 + l16;
            af[t] = *(const v8s*)(&As[ra * 32 + ((quad ^ ((ra >> 1) & 3)) * 8)]);
        }
#pragma unroll
        for (int t = 0; t < 4; t++) {
            const int rb = wn + t * 16 + l16;
            bfr[t] = *(const v8s*)(&Bs[rb * 32 + ((quad ^ ((rb >> 1) & 3)) * 8)]);
        }
#pragma unroll
        for (int i = 0; i < 4; i++)
#pragma unroll
            for (int j = 0; j < 4; j++) acc[i][j] = MFMA(af[i], bfr[j], acc[i][j]);
    }

    if (mode == 2) {
        if (n0 < 2048) {
            __syncthreads();
            float* red = (float*)As;  // [128 rows][2 wn-halves]
#pragma unroll
            for (int i = 0; i < 4; i++) {
#pragma unroll
                for (int r = 0; r < 4; r++) {
                    float ss2 = 0.f;
#pragma unroll
                    for (int j = 0; j < 4; j++) { float v = acc[i][j][r]; ss2 += v * v; }
#pragma unroll
                    for (int off2 = 1; off2 < 16; off2 <<= 1) ss2 += __shfl_xor(ss2, off2);
                    if (l16 == 0) red[(wm + i * 16 + quad * 4 + r) * 2 + (wn >> 6)] = ss2;
                }
            }
            __syncthreads();
            float gv[4];
#pragma unroll
            for (int j = 0; j < 4; j++) gv[j] = g[wn + j * 16 + l16];
#pragma unroll
            for (int i = 0; i < 4; i++) {
#pragma unroll
                for (int r = 0; r < 4; r++) {
                    const int rl = wm + i * 16 + quad * 4 + r;
                    const float rs =
                        rsqrtf((red[rl * 2] + red[rl * 2 + 1]) * (1.f / 128.f) + 1e-6f) * scale;
#pragma unroll
                    for (int j = 0; j < 4; j++)
                        ((short*)C0)[(size_t)(m0 + rl) * 2048 + n0 + wn + j * 16 + l16] =
                            f2bs(acc[i][j][r] * rs * gv[j]);
                }
            }
        } else {
#pragma unroll
            for (int i = 0; i < 4; i++)
#pragma unroll
                for (int r = 0; r < 4; r++) {
                    const int row = m0 + wm + i * 16 + quad * 4 + r;
#pragma unroll
                    for (int j = 0; j < 4; j++)
                        ((short*)C1)[(size_t)row * 512 + n0 - 2048 + wn + j * 16 + l16] =
                            f2bs(acc[i][j][r]);
                }
        }
        return;
    }

    if (mode == 3 && n0 >= 2048) {
        short* C = (short*)C2;
#pragma unroll
        for (int i = 0; i < 4; i++) {
            const int row = m0 + wm + i * 16 + quad * 4;
#pragma unroll
            for (int j = 0; j < 4; j++) {
                const int col = n0 - 2048 + wn + j * 16 + l16;  // h*128+d
                size_t base = ((size_t)((row >> 11) * 16 + (col >> 7)) * 128 + (col & 127)) * 2048
                              + (row & 2047);
                short pk[4];
#pragma unroll
                for (int r = 0; r < 4; r++) pk[r] = f2bs(acc[i][j][r]);
                *(uint2*)(C + base) = *(const uint2*)pk;
            }
        }
        return;
    }

    void* Cb = C0;
    int ld = N, coff = 0;
    if (mode == 3) {
        if (n0 < 1024) { Cb = C0; ld = 1024; coff = 0; }
        else           { Cb = C1; ld = 1024; coff = 1024; }
    }
#pragma unroll
    for (int i = 0; i < 4; i++) {
#pragma unroll
        for (int r = 0; r < 4; r++) {
            const int row = m0 + wm + i * 16 + quad * 4 + r;
#pragma unroll
            for (int j = 0; j < 4; j++) {
                const int col = n0 - coff + wn + j * 16 + l16;
                float v = acc[i][j][r];
                if (mode == 1) ((float*)Cb)[(size_t)row * ld + col] = v;
                else ((short*)Cb)[(size_t)row * ld + col] = f2bs(v);
            }
        }
    }
}

// ------------------------------------------------------------- RMSNorm (k)
__global__ __launch_bounds__(256) void rmsnorm_k(const short* __restrict__ KR,
                                                 const short* __restrict__ KN,
                                                 const float* __restrict__ g,
                                                 short* __restrict__ Y) {
    const int rh = blockIdx.x * 4 + (threadIdx.x >> 6);  // m*16+h
    const int m = rh >> 4, h = rh & 15;
    const int lane = threadIdx.x & 63;
    float a = bs2f(KR[(size_t)m * 1024 + h * 64 + lane]);
    float c = bs2f(KN[(size_t)m * 1024 + h * 64 + lane]);
    float ss = a * a + c * c;
#pragma unroll
    for (int off = 1; off < 64; off <<= 1) ss += __shfl_xor(ss, off);
    float rs = rsqrtf(ss * (1.f / 128.f) + 1e-6f);
    Y[(size_t)rh * 128 + lane] = f2bs(a * rs * g[lane]);
    Y[(size_t)rh * 128 + 64 + lane] = f2bs(c * rs * g[lane + 64]);
}

// ------------------------------------------------------ flash attention (causal)
// Q,K,O: bf16 [B,S,H,D]; V pre-transposed: vT[((b*16+h)*128+d)*S + s].
// ONE WAVE PER BLOCK, 32 q-rows/wave, 64-key tiles, S^T = K Q^T, direct
// global K/V fragment loads (L1/L2 reuse), wave-private LDS for the P
// layout round-trip, no barriers.
// STATIC-SHIFT SOFTMAX: RMSNorm bounds |score*log2e| <= 16.33, so
// p = exp2(s - 20) is exact (softmax shift-invariance), removing the
// running max, all shfl reductions, and the accO rescale. The l-sum is
// computed on the MFMA pipe with a ones-vector B operand, landing in the
// same C-layout rows as accO (no epilogue shuffle either).
#define PSTR 72   // Ps [qrow][key] row stride in shorts

__global__ __launch_bounds__(64) void flash_attn(const short* __restrict__ Q,
                                                 const short* __restrict__ Kb,
                                                 const short* __restrict__ vT,
                                                 short* __restrict__ O, int S) {
    __shared__ short Ps[32 * PSTR];

    const int lane = threadIdx.x & 63;
    const int l16 = lane & 15, quad = lane >> 4;
    const int blk = blockIdx.x;
    const int g = blk >> 3;
    const int bh = (blk & 7) * 4 + (g & 3);     // low bits -> XCD locality
    const int b = bh >> 4, h = bh & 15;
    const int qw = 63 - (g >> 2);               // heavy waves first
    const int wq0 = qw * 32;

    // Q fragments (B-operand): lane l16 = q-col, quad*8+j = d
    v8s bq[2][4];
#pragma unroll
    for (int qs = 0; qs < 2; qs++) {
        const size_t qbase = ((size_t)(b * S + wq0 + qs * 16 + l16) * 16 + h) * 128;
#pragma unroll
        for (int kc = 0; kc < 4; kc++)
            bq[qs][kc] = *(const v8s*)(Q + qbase + kc * 32 + quad * 8);
    }

    const v4f VZ = {0.f, 0.f, 0.f, 0.f};
    v4f accO[2][8];
    v4f accL[2];
#pragma unroll
    for (int qs = 0; qs < 2; qs++) {
        accL[qs] = VZ;
#pragma unroll
        for (int d = 0; d < 8; d++) accO[qs][d] = VZ;
    }

    const short o1 = 0x3F80;  // bf16 1.0
    const v8s vones = {o1, o1, o1, o1, o1, o1, o1, o1};

    const short* const kbh = Kb + ((size_t)b * S * 16 + h) * 128;  // + key*2048 + d
    const short* const vbh = vT + (size_t)bh * 128 * S;            // + d*S + key

    const int nkt = ((wq0 + 31) >> 6) + 1;
    for (int kt = 0; kt < nkt; ++kt) {
        const int k0 = kt * 64;

        // S^T tile = K Q^T: rows = keys (quad*4+r), cols = q (l16)
        v4f sc[2][4];
#pragma unroll
        for (int nt = 0; nt < 4; nt++) {
            v8s ak[4];
            const short* krow = kbh + (size_t)(k0 + nt * 16 + l16) * 2048 + quad * 8;
#pragma unroll
            for (int kc = 0; kc < 4; kc++) ak[kc] = *(const v8s*)(krow + kc * 32);
#pragma unroll
            for (int qs = 0; qs < 2; qs++) {
                v4f s = VZ;
#pragma unroll
                for (int kc = 0; kc < 4; kc++) s = MFMA(ak[kc], bq[qs][kc], s);
                sc[qs][nt] = s;
            }
        }

        // causal mask: only the final (diagonal) tile
        if (kt == nkt - 1) {
#pragma unroll
            for (int qs = 0; qs < 2; qs++) {
                const int qrow = wq0 + qs * 16 + l16;
#pragma unroll
                for (int nt = 0; nt < 4; nt++)
#pragma unroll
                    for (int r = 0; r < 4; r++)
                        if (k0 + nt * 16 + quad * 4 + r > qrow) sc[qs][nt][r] = -1e30f;
            }
        }

        // static-shift softmax numerator: p = 2^(s - 20), no reductions
#pragma unroll
        for (int qs = 0; qs < 2; qs++) {
#pragma unroll
            for (int nt = 0; nt < 4; nt++) {
                short pk[4];
#pragma unroll
                for (int r = 0; r < 4; r++) {
                    float p = exp2f(sc[qs][nt][r] - 20.f);
                    pk[r] = (short)(__float_as_uint(p) >> 16);  // truncating bf16
                }
                *(uint2*)(&Ps[(qs * 16 + l16) * PSTR + nt * 16 + quad * 4]) =
                    *(const uint2*)pk;
            }
        }

        // O += P V ; L += P 1  (P: A-layout from wave-private LDS)
        v8s ap[2][2];
#pragma unroll
        for (int qs = 0; qs < 2; qs++)
#pragma unroll
            for (int kc2 = 0; kc2 < 2; kc2++)
                ap[qs][kc2] =
                    *(const v8s*)(&Ps[(qs * 16 + l16) * PSTR + kc2 * 32 + quad * 8]);
#pragma unroll
        for (int dt = 0; dt < 8; dt++) {
            const short* vrow = vbh + (size_t)(dt * 16 + l16) * S + k0 + quad * 8;
#pragma unroll
            for (int kc2 = 0; kc2 < 2; kc2++) {
                v8s bv = *(const v8s*)(vrow + kc2 * 32);
#pragma unroll
                for (int qs = 0; qs < 2; qs++)
                    accO[qs][dt] = MFMA(ap[qs][kc2], bv, accO[qs][dt]);
            }
        }
#pragma unroll
        for (int qs = 0; qs < 2; qs++)
#pragma unroll
            for (int kc2 = 0; kc2 < 2; kc2++)
                accL[qs] = MFMA(ap[qs][kc2], vones, accL[qs]);
    }

#pragma unroll
    for (int qs = 0; qs < 2; qs++) {
#pragma unroll
        for (int r = 0; r < 4; r++) {
            const int qg = wq0 + qs * 16 + quad * 4 + r;
            const float inv = 1.f / accL[qs][r];   // same C-layout rows as accO
            const size_t obase = ((size_t)(b * S + qg) * 16 + h) * 128;
#pragma unroll
            for (int dt = 0; dt < 8; dt++)
                O[obase + dt * 16 + l16] = f2bs(accO[qs][dt][r] * inv);
        }
    }
}

// ---------------------------------------------------------------------------
extern "C" void kernel_launch(void* const* d_in, const int* in_sizes, int n_in,
                              void* d_out, int out_size, void* d_ws, size_t ws_size,
                              hipStream_t stream) {
    (void)in_sizes; (void)n_in; (void)out_size; (void)ws_size;
    const float* x   = (const float*)d_in[0];
    const float* Wq  = (const float*)d_in[1];
    const float* Wkv = (const float*)d_in[2];
    const float* Wkr = (const float*)d_in[3];
    const float* Wkn = (const float*)d_in[4];
    const float* Wv  = (const float*)d_in[5];
    const float* Wo  = (const float*)d_in[6];
    const float* gq  = (const float*)d_in[7];
    const float* gk  = (const float*)d_in[8];

    const int B = 2, S = 2048, HID = 2048;
    const int M = B * S;  // 4096

    char* ws = (char*)d_ws;
    size_t off = 0;
    auto alloc = [&](size_t bytes) {
        char* p = ws + off;
        off += (bytes + 255) & ~(size_t)255;
        return p;
    };
    short* xb   = (short*)alloc((size_t)M * HID * 2);
    short* WtA  = (short*)alloc((size_t)2560 * 2048 * 2);  // [Wq^T | Wkv^T]
    short* WtB  = (short*)alloc((size_t)4096 * 512 * 2);   // [Wkr^T | Wkn^T | Wv^T]
    short* Wot  = (short*)alloc((size_t)2048 * 2048 * 2);
    short* qb   = (short*)alloc((size_t)M * 2048 * 2);
    short* lat  = (short*)alloc((size_t)M * 512 * 2);
    short* krr  = (short*)alloc((size_t)M * 1024 * 2);
    short* knr  = (short*)alloc((size_t)M * 1024 * 2);
    short* kb   = (short*)alloc((size_t)M * 2048 * 2);
    short* vT   = (short*)alloc((size_t)M * 2048 * 2);  // [B*H][128][S]
    short* ob   = (short*)alloc((size_t)M * 2048 * 2);

    // fused conversion + transposes (single launch)
    prep<<<19456, 256, 0, stream>>>(x, xb, Wq, Wkv, Wkr, Wkn, Wv, Wo, WtA, WtB, Wot);

    // GEMM-A: x @ [Wq | Wkv] -> qb (fused per-head RMSNorm, scale incl log2e) + lat
    gemm_bt<<<dim3(2560 / 128, M / 128), 256, 0, stream>>>(
        xb, WtA, qb, lat, nullptr, M, 2560, 2048, 2, gq,
        0.08838834764831845f * 1.4426950408889634f);

    // GEMM-B: lat @ [Wkr | Wkn | Wv] -> krr, knr, vT(transposed)
    gemm_bt<<<dim3(4096 / 128, M / 128), 256, 0, stream>>>(
        lat, WtB, krr, knr, vT, M, 4096, 512, 3, nullptr, 0.f);
    rmsnorm_k<<<(M * 16) / 4, 256, 0, stream>>>(krr, knr, gk, kb);

    // causal SDPA: one wave (32 q-rows) per block, no barriers, static-shift softmax
    flash_attn<<<dim3(2048), 64, 0, stream>>>(qb, kb, vT, ob, S);

    // GEMM-C: out = o @ Wo (fp32)
    gemm_bt<<<dim3(2048 / 128, M / 128), 256, 0, stream>>>(
        ob, Wot, d_out, nullptr, nullptr, M, 2048, 2048, 1, nullptr, 0.f);
}

// Round 8
// 422.466 us; speedup vs baseline: 1.2499x; 1.1310x over previous
//
#include <hip/hip_runtime.h>
#include <cstdint>
#include <cstddef>

typedef short v8s __attribute__((ext_vector_type(8)));
typedef float v4f __attribute__((ext_vector_type(4)));

__device__ inline float bs2f(short s) {
    return __uint_as_float(((unsigned int)(unsigned short)s) << 16);
}
__device__ inline short f2bs(float f) {
    unsigned int u = __float_as_uint(f);
    unsigned int r = (u + 0x7fffu + ((u >> 16) & 1u)) >> 16;  // RNE
    return (short)r;
}

#define MFMA(a, b, c) __builtin_amdgcn_mfma_f32_16x16x32_bf16((a), (b), (c), 0, 0, 0)

// async global->LDS, 16B per lane, LDS dest = wave-uniform base + lane*16
#define GLOAD_LDS16(g, l)                                                  \
    __builtin_amdgcn_global_load_lds(                                      \
        (const __attribute__((address_space(1))) void*)(g),                \
        (__attribute__((address_space(3))) void*)(l), 16, 0, 0)

// ---------------------------------------------------- fused preprocessing
__global__ __launch_bounds__(256) void prep(const float* __restrict__ x,
                                            short* __restrict__ xb,
                                            const float* __restrict__ Wq,
                                            const float* __restrict__ Wkv,
                                            const float* __restrict__ Wkr,
                                            const float* __restrict__ Wkn,
                                            const float* __restrict__ Wv,
                                            const float* __restrict__ Wo,
                                            short* __restrict__ WtA,
                                            short* __restrict__ WtB,
                                            short* __restrict__ Wot) {
    int blk = blockIdx.x;
    if (blk < 8192) {
        int i = (blk * 256 + threadIdx.x) * 4;
        float4 v = *(const float4*)(x + i);
        short r[4] = {f2bs(v.x), f2bs(v.y), f2bs(v.z), f2bs(v.w)};
        *(uint2*)(xb + i) = *(const uint2*)r;
        return;
    }
    blk -= 8192;
    const float* W;
    short* Wt;
    int K, N, bx, by;
    if (blk < 4096)      { W = Wq;  Wt = WtA;                      K = 2048; N = 2048; bx = blk & 63; by = blk >> 6; }
    else if (blk < 5120) { blk -= 4096; W = Wkv; Wt = WtA + (size_t)2048 * 2048; K = 2048; N = 512;  bx = blk & 15; by = blk >> 4; }
    else if (blk < 5632) { blk -= 5120; W = Wkr; Wt = WtB;                       K = 512;  N = 1024; bx = blk & 31; by = blk >> 5; }
    else if (blk < 6144) { blk -= 5632; W = Wkn; Wt = WtB + (size_t)1024 * 512;  K = 512;  N = 1024; bx = blk & 31; by = blk >> 5; }
    else if (blk < 7168) { blk -= 6144; W = Wv;  Wt = WtB + (size_t)2048 * 512;  K = 512;  N = 2048; bx = blk & 63; by = blk >> 6; }
    else                 { blk -= 7168; W = Wo;  Wt = Wot;                       K = 2048; N = 2048; bx = blk & 63; by = blk >> 6; }

    __shared__ float tile[32][33];
    const int tx = threadIdx.x & 31, ty = threadIdx.x >> 5;  // ty 0..7
    const int n0 = bx * 32, k0 = by * 32;
#pragma unroll
    for (int i = 0; i < 32; i += 8) tile[ty + i][tx] = W[(size_t)(k0 + ty + i) * N + n0 + tx];
    __syncthreads();
#pragma unroll
    for (int i = 0; i < 32; i += 8)
        Wt[(size_t)(n0 + ty + i) * K + k0 + tx] = f2bs(tile[tx][ty + i]);
}

// ----------------------------------------------------------------- GEMM B^T
// C = A[M,K] @ B[K,N], Bt = B^T [N,K] bf16. 128x128 tile, 4 waves, 4x4 MFMA
// 16x16x32 per wave. global_load_lds staging, packed LDS 128x32, XOR swizzle.
// mode 1: f32  C0[M,N]
// mode 2: col<2048 -> fused per-head RMSNorm (g,scale) -> C0 bf16 ld 2048
//         else -> C1 bf16 ld 512 (col-2048)
// mode 3: col<1024 -> C0 ld 1024 ; col<2048 -> C1 ld 1024 ; else V packed to
//         C2 = Vp[bh][kt][d][key] : ((bh*32+kt)*128+d)*64+key  (16KB tiles)
__global__ __launch_bounds__(256) void gemm_bt(const short* __restrict__ A,
                                               const short* __restrict__ Bt,
                                               void* __restrict__ C0,
                                               void* __restrict__ C1,
                                               void* __restrict__ C2,
                                               int M, int N, int K, int mode,
                                               const float* __restrict__ g,
                                               float scale) {
    __shared__ short As[128 * 32];
    __shared__ short Bs[128 * 32];
    const int tid = threadIdx.x;
    const int lane = tid & 63, wave = tid >> 6;
    const int l16 = lane & 15, quad = lane >> 4;
    const int wm = (wave >> 1) * 64, wn = (wave & 1) * 64;
    const int m0 = blockIdx.y * 128, n0 = blockIdx.x * 128;

    const v4f VZ = {0.f, 0.f, 0.f, 0.f};
    v4f acc[4][4];
#pragma unroll
    for (int i = 0; i < 4; i++)
#pragma unroll
        for (int j = 0; j < 4; j++) acc[i][j] = VZ;

    const int r0 = wave * 32 + (lane >> 2);
    const int r1 = r0 + 16;
    const int c0 = ((lane & 3) ^ ((r0 >> 1) & 3)) * 8;
    const int c1 = ((lane & 3) ^ ((r1 >> 1) & 3)) * 8;
    const short* aSrc0 = A + (size_t)(m0 + r0) * K + c0;
    const short* aSrc1 = A + (size_t)(m0 + r1) * K + c1;
    const short* bSrc0 = Bt + (size_t)(n0 + r0) * K + c0;
    const short* bSrc1 = Bt + (size_t)(n0 + r1) * K + c1;
    short* const ldsA0 = &As[(wave * 32) * 32];
    short* const ldsA1 = &As[(wave * 32 + 16) * 32];
    short* const ldsB0 = &Bs[(wave * 32) * 32];
    short* const ldsB1 = &Bs[(wave * 32 + 16) * 32];

    for (int kk = 0; kk < K; kk += 32) {
        __syncthreads();
        GLOAD_LDS16(aSrc0 + kk, ldsA0);
        GLOAD_LDS16(aSrc1 + kk, ldsA1);
        GLOAD_LDS16(bSrc0 + kk, ldsB0);
        GLOAD_LDS16(bSrc1 + kk, ldsB1);
        __syncthreads();

        v8s af[4], bfr[4];
#pragma unroll
        for (int t = 0; t < 4; t++) {
            const int ra = wm + t * 16 + l16;
            af[t] = *(const v8s*)(&As[ra * 32 + ((quad ^ ((ra >> 1) & 3)) * 8)]);
        }
#pragma unroll
        for (int t = 0; t < 4; t++) {
            const int rb = wn + t * 16 + l16;
            bfr[t] = *(const v8s*)(&Bs[rb * 32 + ((quad ^ ((rb >> 1) & 3)) * 8)]);
        }
#pragma unroll
        for (int i = 0; i < 4; i++)
#pragma unroll
            for (int j = 0; j < 4; j++) acc[i][j] = MFMA(af[i], bfr[j], acc[i][j]);
    }

    if (mode == 2) {
        if (n0 < 2048) {
            __syncthreads();
            float* red = (float*)As;  // [128 rows][2 wn-halves]
#pragma unroll
            for (int i = 0; i < 4; i++) {
#pragma unroll
                for (int r = 0; r < 4; r++) {
                    float ss2 = 0.f;
#pragma unroll
                    for (int j = 0; j < 4; j++) { float v = acc[i][j][r]; ss2 += v * v; }
#pragma unroll
                    for (int off2 = 1; off2 < 16; off2 <<= 1) ss2 += __shfl_xor(ss2, off2);
                    if (l16 == 0) red[(wm + i * 16 + quad * 4 + r) * 2 + (wn >> 6)] = ss2;
                }
            }
            __syncthreads();
            float gv[4];
#pragma unroll
            for (int j = 0; j < 4; j++) gv[j] = g[wn + j * 16 + l16];
#pragma unroll
            for (int i = 0; i < 4; i++) {
#pragma unroll
                for (int r = 0; r < 4; r++) {
                    const int rl = wm + i * 16 + quad * 4 + r;
                    const float rs =
                        rsqrtf((red[rl * 2] + red[rl * 2 + 1]) * (1.f / 128.f) + 1e-6f) * scale;
#pragma unroll
                    for (int j = 0; j < 4; j++)
                        ((short*)C0)[(size_t)(m0 + rl) * 2048 + n0 + wn + j * 16 + l16] =
                            f2bs(acc[i][j][r] * rs * gv[j]);
                }
            }
        } else {
#pragma unroll
            for (int i = 0; i < 4; i++)
#pragma unroll
                for (int r = 0; r < 4; r++) {
                    const int row = m0 + wm + i * 16 + quad * 4 + r;
#pragma unroll
                    for (int j = 0; j < 4; j++)
                        ((short*)C1)[(size_t)row * 512 + n0 - 2048 + wn + j * 16 + l16] =
                            f2bs(acc[i][j][r]);
                }
        }
        return;
    }

    if (mode == 3 && n0 >= 2048) {
        // V epilogue -> packed Vp[bh][kt][d][key]; 4 consecutive tokens per 8B store
        short* C = (short*)C2;
#pragma unroll
        for (int i = 0; i < 4; i++) {
            const int row = m0 + wm + i * 16 + quad * 4;  // token (r=0 base)
            const int bq = row >> 11, s = row & 2047;
            const int kt = s >> 6, key = s & 63;
#pragma unroll
            for (int j = 0; j < 4; j++) {
                const int col = n0 - 2048 + wn + j * 16 + l16;  // h*128+d
                const int hh = col >> 7, d = col & 127;
                size_t base = ((size_t)((bq * 16 + hh) * 32 + kt) * 128 + d) * 64 + key;
                short pk[4];
#pragma unroll
                for (int r = 0; r < 4; r++) pk[r] = f2bs(acc[i][j][r]);
                *(uint2*)(C + base) = *(const uint2*)pk;
            }
        }
        return;
    }

    void* Cb = C0;
    int ld = N, coff = 0;
    if (mode == 3) {
        if (n0 < 1024) { Cb = C0; ld = 1024; coff = 0; }
        else           { Cb = C1; ld = 1024; coff = 1024; }
    }
#pragma unroll
    for (int i = 0; i < 4; i++) {
#pragma unroll
        for (int r = 0; r < 4; r++) {
            const int row = m0 + wm + i * 16 + quad * 4 + r;
#pragma unroll
            for (int j = 0; j < 4; j++) {
                const int col = n0 - coff + wn + j * 16 + l16;
                float v = acc[i][j][r];
                if (mode == 1) ((float*)Cb)[(size_t)row * ld + col] = v;
                else ((short*)Cb)[(size_t)row * ld + col] = f2bs(v);
            }
        }
    }
}

// ------------------------------------------------------------- RMSNorm (k)
// writes packed Kp[bh][kt][key][d] : ((bh*32+kt)*64+key)*128+d  (16KB tiles)
__global__ __launch_bounds__(256) void rmsnorm_k(const short* __restrict__ KR,
                                                 const short* __restrict__ KN,
                                                 const float* __restrict__ g,
                                                 short* __restrict__ Y) {
    const int rh = blockIdx.x * 4 + (threadIdx.x >> 6);  // m*16+h
    const int m = rh >> 4, h = rh & 15;
    const int lane = threadIdx.x & 63;
    float a = bs2f(KR[(size_t)m * 1024 + h * 64 + lane]);
    float c = bs2f(KN[(size_t)m * 1024 + h * 64 + lane]);
    float ss = a * a + c * c;
#pragma unroll
    for (int off = 1; off < 64; off <<= 1) ss += __shfl_xor(ss, off);
    float rs = rsqrtf(ss * (1.f / 128.f) + 1e-6f);
    const int b = m >> 11, s = m & 2047;
    const size_t obase = ((size_t)((b * 16 + h) * 32 + (s >> 6)) * 64 + (s & 63)) * 128;
    Y[obase + lane] = f2bs(a * rs * g[lane]);
    Y[obase + 64 + lane] = f2bs(c * rs * g[lane + 64]);
}

// ------------------------------------------------------ flash attention (causal)
// Q,O: bf16 [B,S,H,D]; Kp[bh][kt][64 key][128 d]; Vp[bh][kt][128 d][64 key]
// (16KB contiguous tiles -> no 4KB-stride L1 set thrash, cross-wave L1 reuse).
// 2048 blocks x 2 waves; both waves share (bh,qw)=32 q-rows; wave w takes
// k-tiles w, w+2, ... (static-shift softmax => disjoint-key partials are
// ADDITIVE). One end barrier; wave1 dumps accO/accL to LDS, wave0 combines.
// STATIC-SHIFT SOFTMAX: RMSNorm bounds |score*log2e| <= 16.33 so
// p = exp2(s - 20) is exact; l-sum via ones-vector MFMA (C-layout rows).
#define PSTR 72   // Ps [qrow][key] row stride in shorts

__global__ __launch_bounds__(128) void flash_attn(const short* __restrict__ Q,
                                                  const short* __restrict__ Kp,
                                                  const short* __restrict__ Vp,
                                                  short* __restrict__ O, int S) {
    __shared__ short Ps[2][32 * PSTR];
    __shared__ short Cb[32 * 128];
    __shared__ float Lb[32];

    const int lane = threadIdx.x & 63, w = threadIdx.x >> 6;
    const int l16 = lane & 15, quad = lane >> 4;
    const int blk = blockIdx.x;
    const int g = blk >> 3;
    const int bh = (blk & 7) * 4 + (g & 3);     // low bits -> XCD locality
    const int b = bh >> 4, h = bh & 15;
    const int qw = 63 - (g >> 2);               // heavy blocks first
    const int wq0 = qw * 32;

    // Q fragments (B-operand): lane l16 = q-col, quad*8+j = d
    v8s bq[2][4];
#pragma unroll
    for (int qs = 0; qs < 2; qs++) {
        const size_t qbase = ((size_t)(b * S + wq0 + qs * 16 + l16) * 16 + h) * 128;
#pragma unroll
        for (int kc = 0; kc < 4; kc++)
            bq[qs][kc] = *(const v8s*)(Q + qbase + kc * 32 + quad * 8);
    }

    const v4f VZ = {0.f, 0.f, 0.f, 0.f};
    v4f accO[2][8];
    v4f accL[2];
#pragma unroll
    for (int qs = 0; qs < 2; qs++) {
        accL[qs] = VZ;
#pragma unroll
        for (int d = 0; d < 8; d++) accO[qs][d] = VZ;
    }

    const short o1 = 0x3F80;  // bf16 1.0
    const v8s vones = {o1, o1, o1, o1, o1, o1, o1, o1};

    const short* const kbh = Kp + (size_t)(bh * 32) * 8192;  // + kt*8192
    const short* const vbh = Vp + (size_t)(bh * 32) * 8192;

    const int nkt = (wq0 >> 6) + 1;  // tiles for this q-wave
    for (int kt = w; kt < nkt; kt += 2) {
        const short* const kb = kbh + (size_t)kt * 8192;
        const short* const vb = vbh + (size_t)kt * 8192;

        // S^T tile = K Q^T: rows = keys (quad*4+r), cols = q (l16)
        v4f sc[2][4];
#pragma unroll
        for (int nt = 0; nt < 4; nt++) {
            v8s ak[4];
            const short* krow = kb + (nt * 16 + l16) * 128 + quad * 8;
#pragma unroll
            for (int kc = 0; kc < 4; kc++) ak[kc] = *(const v8s*)(krow + kc * 32);
#pragma unroll
            for (int qs = 0; qs < 2; qs++) {
                v4f s = VZ;
#pragma unroll
                for (int kc = 0; kc < 4; kc++) s = MFMA(ak[kc], bq[qs][kc], s);
                sc[qs][nt] = s;
            }
        }

        // causal mask: only the diagonal tile
        if (kt == nkt - 1) {
            const int k0 = kt * 64;
#pragma unroll
            for (int qs = 0; qs < 2; qs++) {
                const int qrow = wq0 + qs * 16 + l16;
#pragma unroll
                for (int nt = 0; nt < 4; nt++)
#pragma unroll
                    for (int r = 0; r < 4; r++)
                        if (k0 + nt * 16 + quad * 4 + r > qrow) sc[qs][nt][r] = -1e30f;
            }
        }

        // static-shift softmax numerator: p = 2^(s - 20)
#pragma unroll
        for (int qs = 0; qs < 2; qs++) {
#pragma unroll
            for (int nt = 0; nt < 4; nt++) {
                short pk[4];
#pragma unroll
                for (int r = 0; r < 4; r++) {
                    float p = exp2f(sc[qs][nt][r] - 20.f);
                    pk[r] = (short)(__float_as_uint(p) >> 16);  // truncating bf16
                }
                *(uint2*)(&Ps[w][(qs * 16 + l16) * PSTR + nt * 16 + quad * 4]) =
                    *(const uint2*)pk;
            }
        }

        // O += P V ; L += P 1  (P: A-layout from wave-private LDS)
        v8s ap[2][2];
#pragma unroll
        for (int qs = 0; qs < 2; qs++)
#pragma unroll
            for (int kc2 = 0; kc2 < 2; kc2++)
                ap[qs][kc2] =
                    *(const v8s*)(&Ps[w][(qs * 16 + l16) * PSTR + kc2 * 32 + quad * 8]);
#pragma unroll
        for (int dt = 0; dt < 8; dt++) {
            const short* vrow = vb + (dt * 16 + l16) * 64 + quad * 8;
#pragma unroll
            for (int kc2 = 0; kc2 < 2; kc2++) {
                v8s bv = *(const v8s*)(vrow + kc2 * 32);
#pragma unroll
                for (int qs = 0; qs < 2; qs++)
                    accO[qs][dt] = MFMA(ap[qs][kc2], bv, accO[qs][dt]);
            }
        }
#pragma unroll
        for (int qs = 0; qs < 2; qs++)
#pragma unroll
            for (int kc2 = 0; kc2 < 2; kc2++)
                accL[qs] = MFMA(ap[qs][kc2], vones, accL[qs]);
    }

    // combine the two disjoint-key partials (additive under static shift)
    if (w == 1) {
#pragma unroll
        for (int qs = 0; qs < 2; qs++) {
#pragma unroll
            for (int r = 0; r < 4; r++) {
                const int rl = qs * 16 + quad * 4 + r;
#pragma unroll
                for (int dt = 0; dt < 8; dt++)
                    Cb[rl * 128 + dt * 16 + l16] = f2bs(accO[qs][dt][r]);
                if (l16 == 0) Lb[rl] = accL[qs][r];
            }
        }
    }
    __syncthreads();
    if (w == 0) {
#pragma unroll
        for (int qs = 0; qs < 2; qs++) {
#pragma unroll
            for (int r = 0; r < 4; r++) {
                const int rl = qs * 16 + quad * 4 + r;
                const int qg = wq0 + rl;
                const float inv = 1.f / (accL[qs][r] + Lb[rl]);
                const size_t obase = ((size_t)(b * S + qg) * 16 + h) * 128;
#pragma unroll
                for (int dt = 0; dt < 8; dt++)
                    O[obase + dt * 16 + l16] =
                        f2bs((accO[qs][dt][r] + bs2f(Cb[rl * 128 + dt * 16 + l16])) * inv);
            }
        }
    }
}

// ---------------------------------------------------------------------------
extern "C" void kernel_launch(void* const* d_in, const int* in_sizes, int n_in,
                              void* d_out, int out_size, void* d_ws, size_t ws_size,
                              hipStream_t stream) {
    (void)in_sizes; (void)n_in; (void)out_size; (void)ws_size;
    const float* x   = (const float*)d_in[0];
    const float* Wq  = (const float*)d_in[1];
    const float* Wkv = (const float*)d_in[2];
    const float* Wkr = (const float*)d_in[3];
    const float* Wkn = (const float*)d_in[4];
    const float* Wv  = (const float*)d_in[5];
    const float* Wo  = (const float*)d_in[6];
    const float* gq  = (const float*)d_in[7];
    const float* gk  = (const float*)d_in[8];

    const int B = 2, S = 2048, HID = 2048;
    const int M = B * S;  // 4096

    char* ws = (char*)d_ws;
    size_t off = 0;
    auto alloc = [&](size_t bytes) {
        char* p = ws + off;
        off += (bytes + 255) & ~(size_t)255;
        return p;
    };
    short* xb   = (short*)alloc((size_t)M * HID * 2);
    short* WtA  = (short*)alloc((size_t)2560 * 2048 * 2);  // [Wq^T | Wkv^T]
    short* WtB  = (short*)alloc((size_t)4096 * 512 * 2);   // [Wkr^T | Wkn^T | Wv^T]
    short* Wot  = (short*)alloc((size_t)2048 * 2048 * 2);
    short* qb   = (short*)alloc((size_t)M * 2048 * 2);
    short* lat  = (short*)alloc((size_t)M * 512 * 2);
    short* krr  = (short*)alloc((size_t)M * 1024 * 2);
    short* knr  = (short*)alloc((size_t)M * 1024 * 2);
    short* Kp   = (short*)alloc((size_t)M * 2048 * 2);  // [bh][kt][key][d]
    short* Vp   = (short*)alloc((size_t)M * 2048 * 2);  // [bh][kt][d][key]
    short* ob   = (short*)alloc((size_t)M * 2048 * 2);

    // fused conversion + transposes (single launch)
    prep<<<19456, 256, 0, stream>>>(x, xb, Wq, Wkv, Wkr, Wkn, Wv, Wo, WtA, WtB, Wot);

    // GEMM-A: x @ [Wq | Wkv] -> qb (fused per-head RMSNorm, scale incl log2e) + lat
    gemm_bt<<<dim3(2560 / 128, M / 128), 256, 0, stream>>>(
        xb, WtA, qb, lat, nullptr, M, 2560, 2048, 2, gq,
        0.08838834764831845f * 1.4426950408889634f);

    // GEMM-B: lat @ [Wkr | Wkn | Wv] -> krr, knr, Vp(packed)
    gemm_bt<<<dim3(4096 / 128, M / 128), 256, 0, stream>>>(
        lat, WtB, krr, knr, Vp, M, 4096, 512, 3, nullptr, 0.f);
    rmsnorm_k<<<(M * 16) / 4, 256, 0, stream>>>(krr, knr, gk, Kp);

    // causal SDPA: 2048 blocks x 2 key-split waves, packed K/V tiles
    flash_attn<<<dim3(2048), 128, 0, stream>>>(qb, Kp, Vp, ob, S);

    // GEMM-C: out = o @ Wo (fp32)
    gemm_bt<<<dim3(2048 / 128, M / 128), 256, 0, stream>>>(
        ob, Wot, d_out, nullptr, nullptr, M, 2048, 2048, 1, nullptr, 0.f);
}